// Round 7
// baseline (467.109 us; speedup 1.0000x reference)
//
#include <hip/hip_runtime.h>

typedef __attribute__((ext_vector_type(8))) short short8;
typedef __attribute__((ext_vector_type(4))) float f32x4;
typedef __attribute__((ext_vector_type(4))) unsigned int uint4v;

#define HW 65536
#define NPOS 32768

__device__ __forceinline__ unsigned short f2bf(float f) {
  unsigned u = __builtin_bit_cast(unsigned, f);
  u += 0x7fffu + ((u >> 16) & 1u);
  return (unsigned short)(u >> 16);
}
__device__ __forceinline__ float bf2f(unsigned short h) {
  unsigned u = (unsigned)h << 16;
  return __builtin_bit_cast(float, u);
}
// 16B fragment from LDS as two 8B reads (row stride 72B is only 8B-aligned)
__device__ __forceinline__ short8 ld_e16(const unsigned short* p) {
  const uint2 a = *(const uint2*)p;
  const uint2 b = *(const uint2*)(p + 4);
  uint4v u = {a.x, a.y, b.x, b.y};
  return __builtin_bit_cast(short8, u);
}

// ---------------------------------------------------------------------------
// k0: split conv weights to bf16 hi/lo; rows 0-31 = phi, 32-63 = g.
// ---------------------------------------------------------------------------
__global__ __launch_bounds__(256) void k0_prep(
    const float* __restrict__ wphi, const float* __restrict__ wg,
    unsigned short* __restrict__ Whi, unsigned short* __restrict__ Wlo)
{
  const int idx = blockIdx.x * 256 + threadIdx.x;  // 4096 total
  const int u = idx >> 6, c = idx & 63;
  const float w = (u < 32) ? wphi[u * 64 + c] : wg[(u - 32) * 64 + c];
  const unsigned short h = f2bf(w);
  Whi[idx] = h;
  Wlo[idx] = f2bf(w - bf2f(h));
}

// ---------------------------------------------------------------------------
// k1: barrier-free wave-unit conv+exp+att.
// Grid (64, 8), 512 thr = 8 waves, 2 blocks/CU (LDS 73.7 KB).
// Wave owns 64 view-cols (2 chunks of 32). Per chunk:
//   conv: A = x loaded DIRECTLY from global (lane lr = pos row, coalesced),
//         B = W (4 ch-tiles, hi/lo split), D[pos][ch];
//   exp -> wave-private E[128][36] bf16 (rows: 0-63 Ep, 64-127 Eg; pad 36
//         puts b64 writes/reads at the 4-cycle LDS bank floor);
//   att: A = Eg, B = Ep from own E region, K=32, 16 accs (full 64x64).
// No __syncthreads in the loop (same-wave LDS ops are in-order).
// End: 3-barrier LDS-atomic reduction of the 8 waves' att -> attP[b][blk].
// ---------------------------------------------------------------------------
__global__ __launch_bounds__(512, 2) void k1_att(
    const float* __restrict__ x, const unsigned short* __restrict__ Whi,
    const unsigned short* __restrict__ Wlo, float* __restrict__ attP,
    float* __restrict__ sums)
{
  __shared__ unsigned short Ebuf[8 * 128 * 36];   // 73,728 B (also att scratch)

  const int tid = threadIdx.x;
  const int b = blockIdx.y, blk = blockIdx.x;
  const int w = tid >> 6, l = tid & 63;
  const int lr = l & 15, g = l >> 4;
  const float* xb = x + (size_t)b * 64 * HW;
  unsigned short* Ew = Ebuf + w * (128 * 36);

  // conv B-fragments (weights, hi/lo): [ch-tile][kstep]
  short8 wbh[4][2], wbl[4][2];
  #pragma unroll
  for (int cht = 0; cht < 4; ++cht)
    #pragma unroll
    for (int ks = 0; ks < 2; ++ks) {
      const size_t off = (size_t)(cht * 16 + lr) * 64 + ks * 32 + g * 8;
      wbh[cht][ks] = *(const short8*)(Whi + off);
      wbl[cht][ks] = *(const short8*)(Wlo + off);
    }

  f32x4 aacc[4][4] = {};
  float ssp = 0.f, ssg = 0.f;
  const int nw = blk * 512 + w * 64;

  for (int t = 0; t < 2; ++t) {
    const int nb = nw + t * 32;
    #pragma unroll
    for (int pt = 0; pt < 4; ++pt) {
      const int h = pt >> 1, nt = pt & 1;
      const float* xp = xb + (size_t)h * NPOS + nb + nt * 16 + lr;
      // direct global A-fragment: 16 coalesced scalar loads (c = kstep*32+g*8+e)
      float xv[16];
      #pragma unroll
      for (int e = 0; e < 16; ++e)
        xv[e] = xp[(size_t)((e >> 3) * 32 + g * 8 + (e & 7)) * HW];
      short8 ah[2];
      #pragma unroll
      for (int ks = 0; ks < 2; ++ks)
        #pragma unroll
        for (int e = 0; e < 8; ++e)
          ah[ks][e] = (short)f2bf(xv[ks * 8 + e]);
      // conv MFMAs: D[pos 16][ch 64]
      f32x4 cacc[4] = {};
      #pragma unroll
      for (int cht = 0; cht < 4; ++cht)
        #pragma unroll
        for (int ks = 0; ks < 2; ++ks) {
          cacc[cht] = __builtin_amdgcn_mfma_f32_16x16x32_bf16(ah[ks], wbh[cht][ks], cacc[cht], 0, 0, 0);
          cacc[cht] = __builtin_amdgcn_mfma_f32_16x16x32_bf16(ah[ks], wbl[cht][ks], cacc[cht], 0, 0, 0);
        }
      // exp + E write (lane: ch = cht*16+lr fixed, 4 consecutive n)
      #pragma unroll
      for (int cht = 0; cht < 4; ++cht) {
        const float e0 = __expf(cacc[cht][0]);
        const float e1 = __expf(cacc[cht][1]);
        const float e2 = __expf(cacc[cht][2]);
        const float e3 = __expf(cacc[cht][3]);
        if (cht < 2) ssp += (e0 + e1) + (e2 + e3);
        else         ssg += (e0 + e1) + (e2 + e3);
        const int erow = (cht >= 2 ? 64 : 0) + 2 * ((cht & 1) * 16 + lr) + h;
        uint2 pk;
        pk.x = (unsigned)f2bf(e0) | ((unsigned)f2bf(e1) << 16);
        pk.y = (unsigned)f2bf(e2) | ((unsigned)f2bf(e3) << 16);
        *(uint2*)&Ew[erow * 36 + nt * 16 + g * 4] = pk;
      }
    }
    // att partial over this chunk's 32 n (wave-private, no barrier)
    short8 af[4], bp[4];
    #pragma unroll
    for (int ct = 0; ct < 4; ++ct) {
      af[ct] = ld_e16(Ew + (64 + ct * 16 + lr) * 36 + g * 8);  // Eg rows
      bp[ct] = ld_e16(Ew + (ct * 16 + lr) * 36 + g * 8);       // Ep rows
    }
    #pragma unroll
    for (int cg = 0; cg < 4; ++cg)
      #pragma unroll
      for (int cp = 0; cp < 4; ++cp)
        aacc[cg][cp] = __builtin_amdgcn_mfma_f32_16x16x32_bf16(af[cg], bp[cp], aacc[cg][cp], 0, 0, 0);
  }

  // block-level att reduction (E regions dead; reuse as fp32 att scratch)
  __syncthreads();
  float* attL = (float*)Ebuf;
  #pragma unroll
  for (int i = 0; i < 8; ++i) attL[tid + i * 512] = 0.f;
  __syncthreads();
  #pragma unroll
  for (int cg = 0; cg < 4; ++cg)
    #pragma unroll
    for (int cp = 0; cp < 4; ++cp)
      #pragma unroll
      for (int r = 0; r < 4; ++r)
        atomicAdd(&attL[(cg * 16 + g * 4 + r) * 64 + cp * 16 + lr], aacc[cg][cp][r]);
  __syncthreads();
  float* ap = attP + (size_t)(b * 64 + blk) * 4096;
  #pragma unroll
  for (int i = 0; i < 8; ++i) ap[tid + i * 512] = attL[tid + i * 512];

  // softmax denominators
  #pragma unroll
  for (int off = 32; off > 0; off >>= 1) {
    ssp += __shfl_down(ssp, off);
    ssg += __shfl_down(ssg, off);
  }
  if (l == 0) {
    atomicAdd(&sums[b], ssp);
    atomicAdd(&sums[8 + b], ssg);
  }
}

// ---------------------------------------------------------------------------
// k3a: partial-reduce att partials 64 -> 8 per batch. Grid (64).
// ---------------------------------------------------------------------------
__global__ __launch_bounds__(256) void k3a_reduce(
    const float* __restrict__ attP, float* __restrict__ attQ)
{
  const int b = blockIdx.x >> 3, part = blockIdx.x & 7;
  const float* p = attP + (size_t)(b * 64 + part * 8) * 4096;
  float* q = attQ + (size_t)(b * 8 + part) * 4096;
  for (int e = threadIdx.x; e < 4096; e += 256) {
    float s0 = 0.f, s1 = 0.f, s2 = 0.f, s3 = 0.f;
    #pragma unroll
    for (int k = 0; k < 8; k += 4) {
      s0 += p[(size_t)k * 4096 + e];
      s1 += p[(size_t)(k + 1) * 4096 + e];
      s2 += p[(size_t)(k + 2) * 4096 + e];
      s3 += p[(size_t)(k + 3) * 4096 + e];
    }
    q[e] = (s0 + s1) + (s2 + s3);
  }
}

// ---------------------------------------------------------------------------
// k3b: final reduce + N[b][oo=h*64+o][cc=e*64+c] =
//      scale * sum_j ( sum_i wm[o][i]*att[2i+h][2j+e] ) * Wth[j][c] -> bf16 hi/lo
// ---------------------------------------------------------------------------
__global__ __launch_bounds__(1024) void k3b_nmat(
    const float* __restrict__ attQ, const float* __restrict__ sums,
    const float* __restrict__ wm, const float* __restrict__ wtheta,
    unsigned short* __restrict__ Nhi, unsigned short* __restrict__ Nlo)
{
  __shared__ float att_s[4096];
  __shared__ float Mp[2][64][64];
  __shared__ float wms[64][32];
  __shared__ float wts[32][64];
  const int tid = threadIdx.x;
  const int b = blockIdx.x;

  if (tid < 512) {
    if (tid < 256) { for (int k = tid; k < 2048; k += 256) wms[k >> 5][k & 31] = wm[k]; }
    else           { for (int k = tid - 256; k < 2048; k += 256) wts[k >> 6][k & 63] = wtheta[k]; }
  }
  for (int e = tid; e < 4096; e += 1024) {
    const float* p = attQ + (size_t)b * 8 * 4096 + e;
    float s = 0.f;
    #pragma unroll
    for (int q = 0; q < 8; ++q) s += p[(size_t)q * 4096];
    att_s[e] = s;
  }
  __syncthreads();
  for (int idx = tid; idx < 8192; idx += 1024) {
    const int h = idx >> 12, o = (idx >> 6) & 63, d = idx & 63;
    float s = 0.f;
    #pragma unroll
    for (int i = 0; i < 32; ++i)
      s = __builtin_fmaf(wms[o][i], att_s[(2 * i + h) * 64 + d], s);
    Mp[h][o][d] = s;
  }
  __syncthreads();
  const float scale = 1.f / (sums[b] * sums[8 + b]);
  for (int idx = tid; idx < 16384; idx += 1024) {
    const int oo = idx >> 7, cc = idx & 127;
    const int h = oo >> 6, o = oo & 63, e = cc >> 6, c = cc & 63;
    float s = 0.f;
    #pragma unroll
    for (int j = 0; j < 32; ++j)
      s = __builtin_fmaf(Mp[h][o][2 * j + e], wts[j][c], s);
    s *= scale;
    const unsigned short hi = f2bf(s);
    Nhi[(size_t)b * 16384 + idx] = hi;
    Nlo[(size_t)b * 16384 + idx] = f2bf(s - bf2f(hi));
  }
}

// ---------------------------------------------------------------------------
// k5: out[b][o][h*NPOS+n] = sum_cc N[b][h*64+o][cc] * x[b][cc&63][(cc>>6)*NPOS+n]
// Block = 4 waves (256 thr), tile 64n x 128oo; x staged once in LDS
// [n][cc] with pad-132 (b64 ops at bank floor); wave w owns oo [32w,32w+32);
// A = x, B = N (hi/lo in 64 regs) -> float4 stores along n. One barrier.
// ---------------------------------------------------------------------------
__global__ __launch_bounds__(256, 8) void k5_out(
    const float* __restrict__ x, const unsigned short* __restrict__ Nhi,
    const unsigned short* __restrict__ Nlo, float* __restrict__ out)
{
  __shared__ unsigned short Xs[64 * 132];   // 16,896 B
  const int tid = threadIdx.x;
  const int b = blockIdx.y, n0 = blockIdx.x * 64;
  const int w = tid >> 6, l = tid & 63;
  const int lr = l & 15, g = l >> 4;
  const float* xb = x + (size_t)b * 64 * HW;

  // B-fragments: N rows oo = w*32 + j*16 + lr, K=128 (4 ksteps), hi/lo
  short8 bh[2][4], bl[2][4];
  #pragma unroll
  for (int j = 0; j < 2; ++j)
    #pragma unroll
    for (int ks = 0; ks < 4; ++ks) {
      const size_t off = (size_t)b * 16384 + (size_t)(w * 32 + j * 16 + lr) * 128 + ks * 32 + g * 8;
      bh[j][ks] = *(const short8*)(Nhi + off);
      bl[j][ks] = *(const short8*)(Nlo + off);
    }

  // stage x: thread covers cc = half*64 + w*16 .. +15 at n = l (coalesced)
  #pragma unroll
  for (int half = 0; half < 2; ++half) {
    const int cc0 = half * 64 + w * 16;
    const float* xp = xb + (size_t)(w * 16) * HW + (size_t)half * NPOS + n0 + l;
    float v[16];
    #pragma unroll
    for (int i = 0; i < 16; ++i) v[i] = xp[(size_t)i * HW];
    #pragma unroll
    for (int q = 0; q < 4; ++q) {
      uint2 pk;
      pk.x = (unsigned)f2bf(v[q * 4 + 0]) | ((unsigned)f2bf(v[q * 4 + 1]) << 16);
      pk.y = (unsigned)f2bf(v[q * 4 + 2]) | ((unsigned)f2bf(v[q * 4 + 3]) << 16);
      *(uint2*)&Xs[l * 132 + cc0 + q * 4] = pk;
    }
  }
  __syncthreads();

  #pragma unroll
  for (int nt = 0; nt < 4; ++nt) {
    short8 af[4];
    #pragma unroll
    for (int ks = 0; ks < 4; ++ks)
      af[ks] = ld_e16(&Xs[(nt * 16 + lr) * 132 + ks * 32 + g * 8]);
    #pragma unroll
    for (int j = 0; j < 2; ++j) {
      f32x4 acc = {0.f, 0.f, 0.f, 0.f};
      #pragma unroll
      for (int ks = 0; ks < 4; ++ks) {
        acc = __builtin_amdgcn_mfma_f32_16x16x32_bf16(af[ks], bh[j][ks], acc, 0, 0, 0);
        acc = __builtin_amdgcn_mfma_f32_16x16x32_bf16(af[ks], bl[j][ks], acc, 0, 0, 0);
      }
      const int oo = w * 32 + j * 16 + lr;
      float* op = out + (size_t)b * 64 * HW + (size_t)(oo & 63) * HW
                + (size_t)(oo >> 6) * NPOS + n0 + nt * 16 + g * 4;
      *(float4*)op = *(float4*)&acc;
    }
  }
}

// ---------------------------------------------------------------------------
extern "C" void kernel_launch(void* const* d_in, const int* in_sizes, int n_in,
                              void* d_out, int out_size, void* d_ws, size_t ws_size,
                              hipStream_t stream)
{
  const float* x      = (const float*)d_in[0];
  const float* wphi   = (const float*)d_in[1];
  const float* wtheta = (const float*)d_in[2];
  const float* wg     = (const float*)d_in[3];
  const float* wm     = (const float*)d_in[4];
  float* out = (float*)d_out;

  char* ws = (char*)d_ws;
  float* attP         = (float*)ws;                                 //  8,388,608 B used
  unsigned short* Whi = (unsigned short*)(ws + 16777216);           //      8,192 B
  unsigned short* Wlo = (unsigned short*)(ws + 16785408);           //      8,192 B
  unsigned short* Nhi = (unsigned short*)(ws + 16793600);           //    262,144 B
  unsigned short* Nlo = (unsigned short*)(ws + 17055744);           //    262,144 B
  float* sums         = (float*)(ws + 17317888);                    //         64 B
  float* attQ         = (float*)(ws + 17317952);                    //  1,048,576 B

  hipMemsetAsync(sums, 0, 64, stream);
  k0_prep<<<dim3(16), 256, 0, stream>>>(wphi, wg, Whi, Wlo);
  k1_att<<<dim3(64, 8), 512, 0, stream>>>(x, Whi, Wlo, attP, sums);
  k3a_reduce<<<dim3(64), 256, 0, stream>>>(attP, attQ);
  k3b_nmat<<<dim3(8), 1024, 0, stream>>>(attQ, sums, wm, wtheta, Nhi, Nlo);
  k5_out<<<dim3(512, 8), 256, 0, stream>>>(x, Nhi, Nlo, out);
}

// Round 8
// 213.798 us; speedup vs baseline: 2.1848x; 2.1848x over previous
//
#include <hip/hip_runtime.h>

typedef __attribute__((ext_vector_type(8))) short short8;
typedef __attribute__((ext_vector_type(4))) float f32x4;
typedef __attribute__((ext_vector_type(4))) unsigned int uint4v;

#define HW 65536
#define NPOS 32768

__device__ __forceinline__ unsigned short f2bf(float f) {
  unsigned u = __builtin_bit_cast(unsigned, f);
  u += 0x7fffu + ((u >> 16) & 1u);
  return (unsigned short)(u >> 16);
}
__device__ __forceinline__ float bf2f(unsigned short h) {
  unsigned u = (unsigned)h << 16;
  return __builtin_bit_cast(float, u);
}
__device__ __forceinline__ int slot4(int r) { return (r ^ (r >> 2)) & 15; }
// 16B fragment from 8B-aligned LDS (row stride 136B) as two b64 reads
__device__ __forceinline__ short8 ld_e16(const unsigned short* p) {
  const uint2 a = *(const uint2*)p;
  const uint2 b = *(const uint2*)(p + 4);
  uint4v u = {a.x, a.y, b.x, b.y};
  return __builtin_bit_cast(short8, u);
}

// ---------------------------------------------------------------------------
// k0: split conv weights to bf16 hi/lo; rows 0-31 = phi, 32-63 = g.
// ---------------------------------------------------------------------------
__global__ __launch_bounds__(256) void k0_prep(
    const float* __restrict__ wphi, const float* __restrict__ wg,
    unsigned short* __restrict__ Whi, unsigned short* __restrict__ Wlo)
{
  const int idx = blockIdx.x * 256 + threadIdx.x;  // 4096 total
  const int u = idx >> 6, c = idx & 63;
  const float w = (u < 32) ? wphi[u * 64 + c] : wg[(u - 32) * 64 + c];
  const unsigned short h = f2bf(w);
  Whi[idx] = h;
  Wlo[idx] = f2bf(w - bf2f(h));
}

// ---------------------------------------------------------------------------
// k1: conv (A = x direct from global, B = W hi/lo) + exp + att (cooperative).
// Grid (64, 8): block owns 512 view-cols = 8 subtiles of 64. 512 thr = 8 waves.
// Per subtile: wave w computes conv pos-tile w (h=w>>2, quarter w&3, 16 pos x
// 64 ch), exp -> E[buf] (double-buffered, 1 barrier/subtile), then 2 of the 16
// att 16x16 tile-pairs. Next subtile's x loads issue BEFORE the barrier (T14).
// No launch-bounds cap: natural ~140 VGPR, no spill (round-4/7 lesson).
// LDS 34.8 KB. attP: one 64x64 partial per block.
// ---------------------------------------------------------------------------
__global__ __launch_bounds__(512) void k1_att(
    const float* __restrict__ x, const unsigned short* __restrict__ Whi,
    const unsigned short* __restrict__ Wlo, float* __restrict__ attP,
    float* __restrict__ sums)
{
  __shared__ unsigned short E[2][128 * 68];   // [buf][row][68]; rows 0-63 Ep, 64-127 Eg

  const int tid = threadIdx.x;
  const int b = blockIdx.y, blk = blockIdx.x;
  const int w = tid >> 6, l = tid & 63;
  const int lr = l & 15, g = l >> 4;
  const int h = w >> 2, wt = w & 3;           // conv pos-tile: half, quarter
  const int cg = w >> 1, cp0 = (w & 1) * 2;   // att tile-pair base
  const int n0 = blk * 512;
  const float* xb = x + (size_t)b * 64 * HW + (size_t)h * NPOS;

  // conv B-fragments (weights, hi/lo): [ch-tile][kstep]
  short8 wbh[4][2], wbl[4][2];
  #pragma unroll
  for (int cht = 0; cht < 4; ++cht)
    #pragma unroll
    for (int ks = 0; ks < 2; ++ks) {
      const size_t off = (size_t)(cht * 16 + lr) * 64 + ks * 32 + g * 8;
      wbh[cht][ks] = *(const short8*)(Whi + off);
      wbl[cht][ks] = *(const short8*)(Wlo + off);
    }

  f32x4 aacc[2] = {{0.f, 0.f, 0.f, 0.f}, {0.f, 0.f, 0.f, 0.f}};
  float ssp = 0.f, ssg = 0.f;

  // prologue: A-fragment loads for subtile 0 (lane = pos row lr, coalesced 64B/16-lane)
  float xv[16];
  #pragma unroll
  for (int e = 0; e < 16; ++e)
    xv[e] = xb[(size_t)((e >> 3) * 32 + g * 8 + (e & 7)) * HW + n0 + wt * 16 + lr];

  int buf = 0;
  for (int t = 0; t < 8; ++t) {
    // convert A-fragments
    short8 ah[2];
    #pragma unroll
    for (int ks = 0; ks < 2; ++ks)
      #pragma unroll
      for (int e = 0; e < 8; ++e)
        ah[ks][e] = (short)f2bf(xv[ks * 8 + e]);

    // conv: D[pos 16][ch 64], K=64, hi+lo
    f32x4 cacc[4] = {{0.f,0.f,0.f,0.f},{0.f,0.f,0.f,0.f},{0.f,0.f,0.f,0.f},{0.f,0.f,0.f,0.f}};
    #pragma unroll
    for (int cht = 0; cht < 4; ++cht)
      #pragma unroll
      for (int ks = 0; ks < 2; ++ks) {
        cacc[cht] = __builtin_amdgcn_mfma_f32_16x16x32_bf16(ah[ks], wbh[cht][ks], cacc[cht], 0, 0, 0);
        cacc[cht] = __builtin_amdgcn_mfma_f32_16x16x32_bf16(ah[ks], wbl[cht][ks], cacc[cht], 0, 0, 0);
      }

    // exp + E[buf] write: lane owns ch = cht*16+lr, 4 consecutive nn (uint2)
    {
      unsigned short* Eb = E[buf];
      #pragma unroll
      for (int cht = 0; cht < 4; ++cht) {
        const float e0 = __expf(cacc[cht][0]);
        const float e1 = __expf(cacc[cht][1]);
        const float e2 = __expf(cacc[cht][2]);
        const float e3 = __expf(cacc[cht][3]);
        if (cht < 2) ssp += (e0 + e1) + (e2 + e3);
        else         ssg += (e0 + e1) + (e2 + e3);
        const int row = ((cht >= 2) ? 64 : 0) + 2 * ((cht & 1) * 16 + lr) + h;
        uint2 pk;
        pk.x = (unsigned)f2bf(e0) | ((unsigned)f2bf(e1) << 16);
        pk.y = (unsigned)f2bf(e2) | ((unsigned)f2bf(e3) << 16);
        *(uint2*)&E[buf][row * 68 + wt * 16 + g * 4] = pk;
        (void)Eb;
      }
    }

    // prefetch next subtile's A-fragments BEFORE the barrier (latency hidden)
    if (t < 7) {
      const int nn = n0 + (t + 1) * 64 + wt * 16 + lr;
      #pragma unroll
      for (int e = 0; e < 16; ++e)
        xv[e] = xb[(size_t)((e >> 3) * 32 + g * 8 + (e & 7)) * HW + nn];
    }
    __syncthreads();   // E[buf] complete (also protects E[buf^1] reuse)

    // att: wave owns pairs (cg, cp0+j): att[c'g][c'p] += sum_nn Eg*Ep
    #pragma unroll
    for (int ks = 0; ks < 2; ++ks) {
      const short8 ag = ld_e16(&E[buf][(64 + cg * 16 + lr) * 68 + ks * 32 + g * 8]);
      #pragma unroll
      for (int j = 0; j < 2; ++j) {
        const short8 bp = ld_e16(&E[buf][((cp0 + j) * 16 + lr) * 68 + ks * 32 + g * 8]);
        aacc[j] = __builtin_amdgcn_mfma_f32_16x16x32_bf16(ag, bp, aacc[j], 0, 0, 0);
      }
    }
    buf ^= 1;
  }

  // flush att partials (each tile-pair owned by exactly one wave)
  float* ap = attP + (size_t)(b * 64 + blk) * 4096;
  #pragma unroll
  for (int j = 0; j < 2; ++j)
    #pragma unroll
    for (int r = 0; r < 4; ++r)
      ap[(cg * 16 + g * 4 + r) * 64 + (cp0 + j) * 16 + lr] = aacc[j][r];

  // softmax denominators
  #pragma unroll
  for (int off = 32; off > 0; off >>= 1) {
    ssp += __shfl_down(ssp, off);
    ssg += __shfl_down(ssg, off);
  }
  if (l == 0) {
    atomicAdd(&sums[b], ssp);
    atomicAdd(&sums[8 + b], ssg);
  }
}

// ---------------------------------------------------------------------------
// k3a: partial-reduce att partials 64 -> 8 per batch. Grid (64).
// ---------------------------------------------------------------------------
__global__ __launch_bounds__(256) void k3a_reduce(
    const float* __restrict__ attP, float* __restrict__ attQ)
{
  const int b = blockIdx.x >> 3, part = blockIdx.x & 7;
  const float* p = attP + (size_t)(b * 64 + part * 8) * 4096;
  float* q = attQ + (size_t)(b * 8 + part) * 4096;
  for (int e = threadIdx.x; e < 4096; e += 256) {
    float s0 = 0.f, s1 = 0.f, s2 = 0.f, s3 = 0.f;
    #pragma unroll
    for (int k = 0; k < 8; k += 4) {
      s0 += p[(size_t)k * 4096 + e];
      s1 += p[(size_t)(k + 1) * 4096 + e];
      s2 += p[(size_t)(k + 2) * 4096 + e];
      s3 += p[(size_t)(k + 3) * 4096 + e];
    }
    q[e] = (s0 + s1) + (s2 + s3);
  }
}

// ---------------------------------------------------------------------------
// k3b: final reduce + N[b][oo=h*64+o][cc=e*64+c] =
//      scale * sum_j ( sum_i wm[o][i]*att[2i+h][2j+e] ) * Wth[j][c] -> bf16 hi/lo
// ---------------------------------------------------------------------------
__global__ __launch_bounds__(1024) void k3b_nmat(
    const float* __restrict__ attQ, const float* __restrict__ sums,
    const float* __restrict__ wm, const float* __restrict__ wtheta,
    unsigned short* __restrict__ Nhi, unsigned short* __restrict__ Nlo)
{
  __shared__ float att_s[4096];
  __shared__ float Mp[2][64][64];
  __shared__ float wms[64][32];
  __shared__ float wts[32][64];
  const int tid = threadIdx.x;
  const int b = blockIdx.x;

  if (tid < 512) {
    if (tid < 256) { for (int k = tid; k < 2048; k += 256) wms[k >> 5][k & 31] = wm[k]; }
    else           { for (int k = tid - 256; k < 2048; k += 256) wts[k >> 6][k & 63] = wtheta[k]; }
  }
  for (int e = tid; e < 4096; e += 1024) {
    const float* p = attQ + (size_t)b * 8 * 4096 + e;
    float s = 0.f;
    #pragma unroll
    for (int q = 0; q < 8; ++q) s += p[(size_t)q * 4096];
    att_s[e] = s;
  }
  __syncthreads();
  for (int idx = tid; idx < 8192; idx += 1024) {
    const int h = idx >> 12, o = (idx >> 6) & 63, d = idx & 63;
    float s = 0.f;
    #pragma unroll
    for (int i = 0; i < 32; ++i)
      s = __builtin_fmaf(wms[o][i], att_s[(2 * i + h) * 64 + d], s);
    Mp[h][o][d] = s;
  }
  __syncthreads();
  const float scale = 1.f / (sums[b] * sums[8 + b]);
  for (int idx = tid; idx < 16384; idx += 1024) {
    const int oo = idx >> 7, cc = idx & 127;
    const int h = oo >> 6, o = oo & 63, e = cc >> 6, c = cc & 63;
    float s = 0.f;
    #pragma unroll
    for (int j = 0; j < 32; ++j)
      s = __builtin_fmaf(Mp[h][o][2 * j + e], wts[j][c], s);
    s *= scale;
    const unsigned short hi = f2bf(s);
    Nhi[(size_t)b * 16384 + idx] = hi;
    Nlo[(size_t)b * 16384 + idx] = f2bf(s - bf2f(hi));
  }
}

// ---------------------------------------------------------------------------
// k5: out[b][o][h*NPOS+n] = sum_cc N[b][h*64+o][cc] * x[b][cc&63][(cc>>6)*NPOS+n]
// A = x [n][cc], B = N rows (oo) -> lane stores float4 of consecutive n.
// Round-6 version (clean counters), no launch-bounds cap. Grid (512, 8).
// ---------------------------------------------------------------------------
__global__ __launch_bounds__(512) void k5_out(
    const float* __restrict__ x, const unsigned short* __restrict__ Nhi,
    const unsigned short* __restrict__ Nlo, float* __restrict__ out)
{
  __shared__ unsigned short Xh[64 * 128];   // [n][cc] bf16, cc ^ (slot4(n)<<3)
  const int tid = threadIdx.x;
  const int b = blockIdx.y, n0 = blockIdx.x * 64;
  const int w = tid >> 6, l = tid & 63;
  const int lr = l & 15, g = l >> 4;

  // B-fragments: N rows oo = w*16 + lr, K=128 (4 ksteps), hi/lo
  short8 bh[4], bl[4];
  #pragma unroll
  for (int ks = 0; ks < 4; ++ks) {
    const size_t off = (size_t)b * 16384 + (size_t)(w * 16 + lr) * 128 + ks * 32 + g * 8;
    bh[ks] = *(const short8*)(Nhi + off);
    bl[ks] = *(const short8*)(Nlo + off);
  }

  // stage X tile [n][cc]: wave w owns cc in [w*16, w*16+16); lane spans n
  {
    const int ccb = w * 16;
    const int c0 = ccb & 63, e0 = ccb >> 6;
    const float* xp = x + (size_t)b * 64 * HW + (size_t)c0 * HW
                    + (size_t)e0 * NPOS + n0 + l;
    float v[16];
    #pragma unroll
    for (int i = 0; i < 16; ++i) v[i] = xp[(size_t)i * HW];
    short8 pa, pb;
    #pragma unroll
    for (int i = 0; i < 8; ++i) {
      pa[i] = (short)f2bf(v[i]);
      pb[i] = (short)f2bf(v[8 + i]);
    }
    const int s8 = slot4(l) << 3;
    *(short8*)&Xh[l * 128 + (ccb ^ s8)] = pa;
    *(short8*)&Xh[l * 128 + ((ccb + 8) ^ s8)] = pb;
  }
  __syncthreads();

  const int oo = w * 16 + lr;   // this lane's output row (D col = lr)
  float* op = out + (size_t)b * 64 * HW + (size_t)(oo & 63) * HW
            + (size_t)(oo >> 6) * NPOS + n0 + g * 4;

  #pragma unroll
  for (int ct4 = 0; ct4 < 4; ++ct4) {
    f32x4 acc = {0.f, 0.f, 0.f, 0.f};
    const int arow = ct4 * 16 + lr;
    const int sw = slot4(arow) << 3;
    #pragma unroll
    for (int ks = 0; ks < 4; ++ks) {
      const short8 av = *(const short8*)&Xh[arow * 128 + ((ks * 32 + g * 8) ^ sw)];
      acc = __builtin_amdgcn_mfma_f32_16x16x32_bf16(av, bh[ks], acc, 0, 0, 0);
      acc = __builtin_amdgcn_mfma_f32_16x16x32_bf16(av, bl[ks], acc, 0, 0, 0);
    }
    // D: row (n within subtile) = g*4 + r, col = lr -> float4 store
    *(float4*)(op + ct4 * 16) = *(float4*)&acc;
  }
}

// ---------------------------------------------------------------------------
extern "C" void kernel_launch(void* const* d_in, const int* in_sizes, int n_in,
                              void* d_out, int out_size, void* d_ws, size_t ws_size,
                              hipStream_t stream)
{
  const float* x      = (const float*)d_in[0];
  const float* wphi   = (const float*)d_in[1];
  const float* wtheta = (const float*)d_in[2];
  const float* wg     = (const float*)d_in[3];
  const float* wm     = (const float*)d_in[4];
  float* out = (float*)d_out;

  char* ws = (char*)d_ws;
  float* attP         = (float*)ws;                                 //  8,388,608 B
  unsigned short* Whi = (unsigned short*)(ws + 16777216);           //      8,192 B
  unsigned short* Wlo = (unsigned short*)(ws + 16785408);           //      8,192 B
  unsigned short* Nhi = (unsigned short*)(ws + 16793600);           //    262,144 B
  unsigned short* Nlo = (unsigned short*)(ws + 17055744);           //    262,144 B
  float* sums         = (float*)(ws + 17317888);                    //         64 B
  float* attQ         = (float*)(ws + 17317952);                    //  1,048,576 B

  hipMemsetAsync(sums, 0, 64, stream);
  k0_prep<<<dim3(16), 256, 0, stream>>>(wphi, wg, Whi, Wlo);
  k1_att<<<dim3(64, 8), 512, 0, stream>>>(x, Whi, Wlo, attP, sums);
  k3a_reduce<<<dim3(64), 256, 0, stream>>>(attP, attQ);
  k3b_nmat<<<dim3(8), 1024, 0, stream>>>(attQ, sums, wm, wtheta, Nhi, Nlo);
  k5_out<<<dim3(512, 8), 512, 0, stream>>>(x, Nhi, Nlo, out);
}